// Round 7
// baseline (270.137 us; speedup 1.0000x reference)
//
#include <hip/hip_runtime.h>

typedef unsigned short u16;
typedef __attribute__((ext_vector_type(8))) _Float16 f16x8;
typedef __attribute__((ext_vector_type(4))) _Float16 f16x4;
typedef __attribute__((ext_vector_type(2))) _Float16 f16x2;
typedef __attribute__((ext_vector_type(4))) float f32x4;

#define DEV static __device__ __forceinline__

DEV float bf2f(u16 h){ unsigned u = ((unsigned)h) << 16; return __builtin_bit_cast(float, u); }
DEV u16 f2bf(float f){ unsigned u = __builtin_bit_cast(unsigned, f); u += 0x7FFFu + ((u >> 16) & 1u); return (u16)(u >> 16); }
DEV u16 f2h(float f){ _Float16 h = (_Float16)f; return __builtin_bit_cast(u16, h); }
DEV float h2f(u16 h){ return (float)__builtin_bit_cast(_Float16, h); }

DEV f32x4 mfma16(f16x8 a, f16x8 b, f32x4 c){
  return __builtin_amdgcn_mfma_f32_16x16x32_f16(a, b, c, 0, 0, 0);
}

// relu(fp16_a + fp16_b) packed pair -> v_pk_add_f16 + v_pk_max_f16
DEV unsigned rap(unsigned a, unsigned b){
  f16x2 ha = __builtin_bit_cast(f16x2, a);
  f16x2 hb = __builtin_bit_cast(f16x2, b);
  f16x2 s = ha + hb;
  const _Float16 z = (_Float16)0;
  s.x = s.x > z ? s.x : z;
  s.y = s.y > z ? s.y : z;
  return __builtin_bit_cast(unsigned, s);
}

DEV f16x8 build_frag(uint4 s, uint4 r){
  uint4 o;
  o.x = rap(s.x, r.x); o.y = rap(s.y, r.y);
  o.z = rap(s.z, r.z); o.w = rap(s.w, r.w);
  return __builtin_bit_cast(f16x8, o);
}

// Sizes: B=64, N=64, F=64, H=256, O=64, T=4, E=4032
// ws layout (bytes): FLAG@0 | W1T@256 | W2T@262400 | OW1T@393472 | OW2T@459008
//  | OW3T@590080 | B1@622848 | B2@624896 | OB1@625408 | OB2@625920 | OB3@626432
//  | S1@626688 (8.4MB) | R1@9015296 (8.4MB) | AGG(f32)@17403904 (1MB)
//  | RTT(fp16 [t][b][j][i])@18452480 (2MB) -> end 20549632 (under proven 21.04MB)
#define OFF_W1T  256
#define OFF_W2T  262400
#define OFF_OW1T 393472
#define OFF_OW2T 459008
#define OFF_OW3T 590080
#define OFF_B1   622848
#define OFF_B2   624896
#define OFF_OB1  625408
#define OFF_OB2  625920
#define OFF_OB3  626432
#define OFF_S1   626688
#define OFF_R1   9015296
#define OFF_AGG  17403904
#define OFF_RTT  18452480

DEV float ldin(const void* p, int i, int isbf){
  return isbf ? bf2f(((const u16*)p)[i]) : ((const float*)p)[i];
}

// in-block dtype sniff: wave 0 ballots on x's even u16s, LDS-broadcast.
DEV int sniff_isbf(const u16* x, int tid, int* sflag){
  if(tid < 64){
    u16 u = x[2 * tid];
    int e = (u >> 7) & 0xFF;
    int ok = (e >= 103 && e <= 143) ? 1 : 0;
    unsigned long long m = __ballot(ok);
    if(tid == 0) *sflag = (__builtin_popcountll(m) >= 40) ? 1 : 0;
  }
  __syncthreads();
  return *sflag;
}

// ---------------- K0: prep — weight transposes + bias converts + rel_type transpose + flag ----------------
__global__ __launch_bounds__(256) void k_prep(const void* __restrict__ x, const void* __restrict__ rt,
    const void* __restrict__ w1, const void* __restrict__ b1,
    const void* __restrict__ w2, const void* __restrict__ b2,
    const void* __restrict__ ow1, const void* __restrict__ ob1,
    const void* __restrict__ ow2, const void* __restrict__ ob2,
    const void* __restrict__ ow3, const void* __restrict__ ob3,
    char* __restrict__ ws){
  __shared__ float tile[32][33];
  __shared__ u16 sT[16384];          // [t][j][i] for rel transpose
  __shared__ int sflag;
  const int bid = blockIdx.x, tid = threadIdx.x;
  const int isbf = sniff_isbf((const u16*)x, tid, &sflag);
  if(bid >= 313){                    // rel_type transpose: one block per b
    const int b = bid - 313;
    uint4 zz; zz.x = zz.y = zz.z = zz.w = 0;
    #pragma unroll
    for(int it=0; it<8; ++it) ((uint4*)sT)[tid + it*256] = zz;
    __syncthreads();
    const int base = b * 16128;
    #pragma unroll 1
    for(int it=0; it<63; ++it){
      int c = tid + it*256;          // [0,16128)
      int e = c >> 2, tt = c & 3;
      int i = e / 63, jr = e - i*63;
      int j = jr + (jr >= i ? 1 : 0);
      sT[(tt*64 + j)*64 + i] = f2h(ldin(rt, base + c, isbf));
    }
    __syncthreads();
    u16* RTT = (u16*)(ws + OFF_RTT);
    #pragma unroll
    for(int tt=0; tt<4; ++tt){
      uint4* dst = (uint4*)(RTT + ((tt*64 + b)*64)*64);
      const uint4* srcv = (const uint4*)(sT + tt*4096);
      #pragma unroll
      for(int it=0; it<2; ++it){
        int c = tid + it*256;        // [0,512)
        dst[c] = srcv[c];
      }
    }
    return;
  }
  if(bid == 312){ if(tid == 0) *(int*)ws = isbf; return; }
  if(bid >= 304){                    // biases: 1856 elems
    int n = (bid - 304) * 256 + tid;
    if(n < 1024){ ((u16*)(ws+OFF_B1))[n] = f2h(ldin(b1, n, isbf)); return; }
    n -= 1024;
    if(n < 256){ ((u16*)(ws+OFF_B2))[n] = f2h(ldin(b2, n, isbf)); return; }
    n -= 256;
    if(n < 256){ ((u16*)(ws+OFF_OB1))[n] = f2h(ldin(ob1, n, isbf)); return; }
    n -= 256;
    if(n < 256){ ((u16*)(ws+OFF_OB2))[n] = f2h(ldin(ob2, n, isbf)); return; }
    n -= 256;
    if(n < 64){ ((u16*)(ws+OFF_OB3))[n] = f2h(ldin(ob3, n, isbf)); }
    return;
  }
  // tiled transpose+convert: src [G][R][C] -> dst [G][C][R]
  const void* src; u16* dst; int R, C, off, r0, c0;
  if(bid < 128){ int g = bid >> 5, tt = bid & 31;
    src = w1; dst = (u16*)(ws + OFF_W1T); R = 128; C = 256; off = g * 32768;
    r0 = (tt >> 3) << 5; c0 = (tt & 7) << 5;
  } else if(bid < 192){ int bb = bid - 128; int g = bb >> 4, tt = bb & 15;
    src = w2; dst = (u16*)(ws + OFF_W2T); R = 256; C = 64; off = g * 16384;
    r0 = (tt >> 1) << 5; c0 = (tt & 1) << 5;
  } else if(bid < 224){ int bb = bid - 192;
    src = ow1; dst = (u16*)(ws + OFF_OW1T); R = 128; C = 256; off = 0;
    r0 = (bb >> 3) << 5; c0 = (bb & 7) << 5;
  } else if(bid < 288){ int bb = bid - 224;
    src = ow2; dst = (u16*)(ws + OFF_OW2T); R = 256; C = 256; off = 0;
    r0 = (bb >> 3) << 5; c0 = (bb & 7) << 5;
  } else { int bb = bid - 288;
    src = ow3; dst = (u16*)(ws + OFF_OW3T); R = 256; C = 64; off = 0;
    r0 = (bb >> 1) << 5; c0 = (bb & 1) << 5;
  }
  int tx = tid & 31, ty = tid >> 5;
  #pragma unroll
  for(int p = 0; p < 4; ++p){
    int r = ty + p * 8;
    tile[r][tx] = ldin(src, off + (r0 + r) * C + c0 + tx, isbf);
  }
  __syncthreads();
  #pragma unroll
  for(int p = 0; p < 4; ++p){
    int c = ty + p * 8;
    dst[off + (c0 + c) * R + r0 + tx] = f2h(tile[tx][c]);
  }
}

// ---------------- K1: S1/R1 = x @ w1-half (+b1 on receiver half); also zeroes AGG ----------------
__global__ __launch_bounds__(256) void k_s1r1(const void* __restrict__ x, const u16* __restrict__ W1T,
    const u16* __restrict__ B1c, u16* __restrict__ S1, u16* __restrict__ R1,
    float* __restrict__ AGG, const int* __restrict__ flag){
  __shared__ __align__(16) u16 sX[64][72];
  __shared__ __align__(16) u16 sW[256][72];
  const int tid = threadIdx.x, bid = blockIdx.x;
  const int b = bid & 63, th = bid >> 6, t = th >> 1, half = th & 1;
  const int isbf = *flag;
  {   // zero this block's 2KB slice of AGG (512 blocks x 2048B = 1MB exactly)
    float2 zz; zz.x = 0.f; zz.y = 0.f;
    ((float2*)AGG)[bid*256 + tid] = zz;
  }
  {
    if(isbf){
      const uint4* src = (const uint4*)((const u16*)x + b*4096);
      #pragma unroll
      for(int it=0; it<2; ++it){
        int c = tid + it*256; int row = c >> 3, col = (c & 7) * 8;
        uint4 v = src[c];
        const u16* pv = (const u16*)&v;
        u16 o[8];
        #pragma unroll
        for(int e=0;e<8;++e) o[e] = f2h(bf2f(pv[e]));
        *(uint4*)&sX[row][col] = *(const uint4*)o;
      }
    } else {
      const float* src = (const float*)x + b*4096;
      #pragma unroll
      for(int it=0; it<2; ++it){
        int c = tid + it*256; int row = c >> 3, col = (c & 7) * 8;
        u16 o[8];
        #pragma unroll
        for(int e=0;e<8;++e) o[e] = f2h(src[c*8 + e]);
        *(uint4*)&sX[row][col] = *(const uint4*)o;
      }
    }
    const u16* base = W1T + t*32768 + half*64;
    #pragma unroll
    for(int it=0; it<8; ++it){
      int c = tid + it*256; int h = c >> 3, kc = (c & 7) * 8;
      *(uint4*)&sW[h][kc] = *(const uint4*)(base + h*128 + kc);
    }
  }
  __syncthreads();
  const int wv = tid >> 6, l = tid & 63, ml = l & 15, q = l >> 4;
  const f32x4 z = {0.f,0.f,0.f,0.f};
  f32x4 acc[4][4];
  #pragma unroll
  for(int mt=0;mt<4;++mt){ acc[mt][0]=z; acc[mt][1]=z; acc[mt][2]=z; acc[mt][3]=z; }
  #pragma unroll
  for(int ks=0; ks<2; ++ks){
    const int kb = ks*32 + q*8;
    f16x8 af[4], bff[4];
    #pragma unroll
    for(int mt=0;mt<4;++mt) af[mt] = *(const f16x8*)&sX[mt*16 + ml][kb];
    #pragma unroll
    for(int nt=0;nt<4;++nt) bff[nt] = *(const f16x8*)&sW[wv*64 + nt*16 + ml][kb];
    #pragma unroll
    for(int mt=0;mt<4;++mt)
      #pragma unroll
      for(int nt=0;nt<4;++nt)
        acc[mt][nt] = mfma16(af[mt], bff[nt], acc[mt][nt]);
  }
  u16* dst = (half ? R1 : S1) + (t*64 + b)*16384;
  #pragma unroll
  for(int nt=0;nt<4;++nt){
    const int h = wv*64 + nt*16 + ml;
    const float bias = half ? h2f(B1c[t*256 + h]) : 0.0f;
    #pragma unroll
    for(int mt=0;mt<4;++mt)
      #pragma unroll
      for(int r=0;r<4;++r){
        int irow = mt*16 + q*4 + r;
        dst[irow*256 + h] = f2h(acc[mt][nt][r] + bias);
      }
  }
}

// ---------------- K2: per-edge layer-2 + weighted aggregation ----------------
// grid 512 = (t:4) x (b:64) x (jg:2). 4 waves share t; S1[t][b]+W2T[t] in padded LDS.
// One acc set per wave (no spill); ru ping-pong prefetch; coalesced atomic flush.
__global__ __launch_bounds__(256, 2) void k_edge(const u16* __restrict__ RTT,
    const u16* __restrict__ W2T, const u16* __restrict__ B2c,
    const u16* __restrict__ S1, const u16* __restrict__ R1,
    float* __restrict__ AGG){
  __shared__ __align__(16) u16 sS1[64][264];   // [i][k], +8 pad
  __shared__ __align__(16) u16 sW2[64][264];   // [o][k], +8 pad
  __shared__ __align__(16) u16 sRT[32][64];    // [j-local][i] fp16, 256 uint4
  __shared__ float sOut[2048];                 // [j-local][o]
  const int tid = threadIdx.x, bid = blockIdx.x;
  const int t = bid >> 7, b = (bid >> 1) & 63, jg = bid & 1, j0 = jg * 32;
  {
    const uint4* s1p = (const uint4*)(S1 + (t*64 + b)*16384);
    const uint4* w2p = (const uint4*)(W2T + t*16384);
    #pragma unroll
    for(int it=0; it<8; ++it){
      int c = tid + it*256;                 // 0..2047
      int row = c >> 5, col = (c & 31) * 8;
      *(uint4*)&sS1[row][col] = s1p[c];
      *(uint4*)&sW2[row][col] = w2p[c];
    }
    // sRT is 32*64 u16 = 4096 B = 256 uint4: one per lane (R6 bug: loaded only half)
    ((uint4*)sRT)[tid] = ((const uint4*)(RTT + ((t*64 + b)*64 + j0)*64))[tid];
  }
  __syncthreads();
  const int w = tid >> 6, l = tid & 63, ml = l & 15, q = l >> 4;
  float bias2[4];
  #pragma unroll
  for(int nt=0;nt<4;++nt) bias2[nt] = h2f(B2c[t*64 + nt*16 + ml]);
  const u16* r1b = R1 + (t*64 + b)*16384 + j0*256;
  const f32x4 z = {0.f,0.f,0.f,0.f};
  uint4 ru[8], run[8];
  {
    const u16* rp = r1b + (w*8)*256;
    #pragma unroll
    for(int ks=0;ks<8;++ks) ru[ks] = *(const uint4*)(rp + ks*32 + q*8);
  }
  #pragma unroll 1
  for(int jp=0; jp<8; ++jp){
    const int jl = w*8 + jp;
    if(jp < 7){                 // prefetch next receiver row while MFMAs run
      const u16* rp = r1b + (jl + 1)*256;
      #pragma unroll
      for(int ks=0;ks<8;++ks) run[ks] = *(const uint4*)(rp + ks*32 + q*8);
    }
    f32x4 acc[4][4];
    #pragma unroll
    for(int mt=0;mt<4;++mt){ acc[mt][0]=z; acc[mt][1]=z; acc[mt][2]=z; acc[mt][3]=z; }
    #pragma unroll
    for(int ks=0;ks<8;++ks){
      const int kb = ks*32 + q*8;
      f16x8 bf[4];
      #pragma unroll
      for(int nt=0;nt<4;++nt) bf[nt] = *(const f16x8*)&sW2[nt*16 + ml][kb];
      #pragma unroll
      for(int mt=0;mt<4;++mt){
        uint4 su = *(const uint4*)&sS1[mt*16 + ml][kb];
        f16x8 af = build_frag(su, ru[ks]);
        #pragma unroll
        for(int nt=0;nt<4;++nt) acc[mt][nt] = mfma16(af, bf[nt], acc[mt][nt]);
      }
    }
    // epilogue: relu(C + b2), weighted column-sum over sender rows i
    float cs[4] = {0.f,0.f,0.f,0.f};
    #pragma unroll
    for(int mt=0;mt<4;++mt){
      f16x4 rv = *(const f16x4*)&sRT[jl][mt*16 + q*4];
      #pragma unroll
      for(int nt=0;nt<4;++nt)
        #pragma unroll
        for(int r=0;r<4;++r)
          cs[nt] += fmaxf(acc[mt][nt][r] + bias2[nt], 0.0f) * (float)rv[r];
    }
    #pragma unroll
    for(int nt=0;nt<4;++nt){
      float v = cs[nt];
      v += __shfl_xor(v, 16, 64);
      v += __shfl_xor(v, 32, 64);
      if(q == 0) sOut[jl*64 + nt*16 + ml] = v;
    }
    if(jp < 7){
      #pragma unroll
      for(int ks=0;ks<8;++ks) ru[ks] = run[ks];
    }
  }
  __syncthreads();
  float* aggp = AGG + (b*64 + j0)*64;
  #pragma unroll
  for(int it=0; it<8; ++it){
    int c = tid + it*256;
    atomicAdd(&aggp[c], sOut[c]);
  }
}

// ---------------- K3: node MLP (aug=[x,agg] -> 256 -> 256 -> 64) ----------------
__global__ __launch_bounds__(256) void k_node(const void* __restrict__ x, const float* __restrict__ AGG,
    const u16* __restrict__ OW1T, const u16* __restrict__ OB1c,
    const u16* __restrict__ OW2T, const u16* __restrict__ OB2c,
    const u16* __restrict__ OW3T, const u16* __restrict__ OB3c,
    void* __restrict__ out, const int* __restrict__ flag){
  __shared__ __align__(16) u16 sA[64][136];
  __shared__ __align__(16) u16 sH[64][264];
  __shared__ __align__(16) u16 sH2[64][264];
  __shared__ __align__(16) u16 sW[64][264];
  const int tid = threadIdx.x, bb = blockIdx.x;
  const int isbf = *flag;
  {
    if(isbf){
      const uint4* src = (const uint4*)((const u16*)x + bb*4096);
      #pragma unroll
      for(int it=0; it<2; ++it){
        int c = tid + it*256; int row = c >> 3, col = (c & 7)*8;
        uint4 v = src[c];
        const u16* pv = (const u16*)&v;
        u16 o[8];
        #pragma unroll
        for(int e=0;e<8;++e) o[e] = f2h(bf2f(pv[e]));
        *(uint4*)&sA[row][col] = *(const uint4*)o;
      }
    } else {
      const float* src = (const float*)x + bb*4096;
      #pragma unroll
      for(int it=0; it<2; ++it){
        int c = tid + it*256; int row = c >> 3, col = (c & 7)*8;
        u16 o[8];
        #pragma unroll
        for(int e=0;e<8;++e) o[e] = f2h(src[c*8 + e]);
        *(uint4*)&sA[row][col] = *(const uint4*)o;
      }
    }
    const float* ag = AGG + bb*4096;
    #pragma unroll
    for(int it=0; it<16; ++it){
      int c = tid + it*256; int row = c >> 6, col = c & 63;
      sA[row][64 + col] = f2h(ag[c]);
    }
  }
  const int wv = tid >> 6, l = tid & 63, ml = l & 15, q = l >> 4;
  const f32x4 z = {0.f,0.f,0.f,0.f};
  __syncthreads();
  // L1: K=128 from sA -> sH (256 cols in 4 chunks of 64)
  for(int nc=0; nc<4; ++nc){
    #pragma unroll
    for(int it=0; it<4; ++it){
      int c = tid + it*256; int h = c >> 4, kc = (c & 15)*8;
      *(uint4*)&sW[h][kc] = *(const uint4*)(OW1T + (nc*64 + h)*128 + kc);
    }
    __syncthreads();
    f32x4 acc[4] = {z,z,z,z};
    #pragma unroll
    for(int ks=0; ks<4; ++ks){
      int kb = ks*32 + q*8;
      f16x8 bfrag = *(const f16x8*)&sW[wv*16 + ml][kb];
      #pragma unroll
      for(int mt=0;mt<4;++mt){
        f16x8 afrag = *(const f16x8*)&sA[mt*16 + ml][kb];
        acc[mt] = mfma16(afrag, bfrag, acc[mt]);
      }
    }
    const int h = nc*64 + wv*16 + ml;
    const float bias = h2f(OB1c[h]);
    #pragma unroll
    for(int mt=0;mt<4;++mt)
      #pragma unroll
      for(int r=0;r<4;++r){
        int row = mt*16 + q*4 + r;
        sH[row][h] = f2h(fmaxf(acc[mt][r] + bias, 0.0f));
      }
    __syncthreads();
  }
  // L2: K=256 from sH -> sH2
  for(int nc=0; nc<4; ++nc){
    #pragma unroll
    for(int it=0; it<8; ++it){
      int c = tid + it*256; int h = c >> 5, kc = (c & 31)*8;
      *(uint4*)&sW[h][kc] = *(const uint4*)(OW2T + (nc*64 + h)*256 + kc);
    }
    __syncthreads();
    f32x4 acc[4] = {z,z,z,z};
    #pragma unroll
    for(int ks=0; ks<8; ++ks){
      int kb = ks*32 + q*8;
      f16x8 bfrag = *(const f16x8*)&sW[wv*16 + ml][kb];
      #pragma unroll
      for(int mt=0;mt<4;++mt){
        f16x8 afrag = *(const f16x8*)&sH[mt*16 + ml][kb];
        acc[mt] = mfma16(afrag, bfrag, acc[mt]);
      }
    }
    const int h = nc*64 + wv*16 + ml;
    const float bias = h2f(OB2c[h]);
    #pragma unroll
    for(int mt=0;mt<4;++mt)
      #pragma unroll
      for(int r=0;r<4;++r){
        int row = mt*16 + q*4 + r;
        sH2[row][h] = f2h(fmaxf(acc[mt][r] + bias, 0.0f));
      }
    __syncthreads();
  }
  // L3: K=256 from sH2 -> out (no relu)
  {
    #pragma unroll
    for(int it=0; it<8; ++it){
      int c = tid + it*256; int h = c >> 5, kc = (c & 31)*8;
      *(uint4*)&sW[h][kc] = *(const uint4*)(OW3T + h*256 + kc);
    }
    __syncthreads();
    f32x4 acc[4] = {z,z,z,z};
    #pragma unroll
    for(int ks=0; ks<8; ++ks){
      int kb = ks*32 + q*8;
      f16x8 bfrag = *(const f16x8*)&sW[wv*16 + ml][kb];
      #pragma unroll
      for(int mt=0;mt<4;++mt){
        f16x8 afrag = *(const f16x8*)&sH2[mt*16 + ml][kb];
        acc[mt] = mfma16(afrag, bfrag, acc[mt]);
      }
    }
    const int o = wv*16 + ml;
    const float bias = h2f(OB3c[o]);
    #pragma unroll
    for(int mt=0;mt<4;++mt)
      #pragma unroll
      for(int r=0;r<4;++r){
        int row = mt*16 + q*4 + r;
        float v = acc[mt][r] + bias;
        int idx = bb*4096 + row*64 + o;
        if(isbf) ((u16*)out)[idx] = f2bf(v);
        else     ((float*)out)[idx] = v;
      }
  }
}

extern "C" void kernel_launch(void* const* d_in, const int* in_sizes, int n_in,
                              void* d_out, int out_size, void* d_ws, size_t ws_size,
                              hipStream_t stream){
  (void)in_sizes; (void)n_in; (void)out_size; (void)ws_size;
  char* ws = (char*)d_ws;
  u16* W1T  = (u16*)(ws + OFF_W1T);
  u16* W2T  = (u16*)(ws + OFF_W2T);
  u16* OW1T = (u16*)(ws + OFF_OW1T);
  u16* OW2T = (u16*)(ws + OFF_OW2T);
  u16* OW3T = (u16*)(ws + OFF_OW3T);
  u16* B1c  = (u16*)(ws + OFF_B1);
  u16* B2c  = (u16*)(ws + OFF_B2);
  u16* OB1c = (u16*)(ws + OFF_OB1);
  u16* OB2c = (u16*)(ws + OFF_OB2);
  u16* OB3c = (u16*)(ws + OFF_OB3);
  u16* S1   = (u16*)(ws + OFF_S1);
  u16* R1   = (u16*)(ws + OFF_R1);
  float* AGG = (float*)(ws + OFF_AGG);
  u16* RTT  = (u16*)(ws + OFF_RTT);
  const int* flag = (const int*)ws;

  k_prep<<<377, 256, 0, stream>>>(d_in[0], d_in[1], d_in[4], d_in[5], d_in[6], d_in[7],
                                  d_in[8], d_in[9], d_in[10], d_in[11], d_in[12], d_in[13], ws);
  k_s1r1<<<512, 256, 0, stream>>>(d_in[0], W1T, B1c, S1, R1, AGG, flag);
  k_edge<<<512, 256, 0, stream>>>(RTT, W2T, B2c, S1, R1, AGG);
  k_node<<<64, 256, 0, stream>>>(d_in[0], AGG, OW1T, OB1c, OW2T, OB2c, OW3T, OB3c, d_out, flag);
}

// Round 8
// 193.301 us; speedup vs baseline: 1.3975x; 1.3975x over previous
//
#include <hip/hip_runtime.h>

typedef unsigned short u16;
typedef __attribute__((ext_vector_type(8))) _Float16 f16x8;
typedef __attribute__((ext_vector_type(4))) _Float16 f16x4;
typedef __attribute__((ext_vector_type(2))) _Float16 f16x2;
typedef __attribute__((ext_vector_type(4))) float f32x4;

#define DEV static __device__ __forceinline__

DEV float bf2f(u16 h){ unsigned u = ((unsigned)h) << 16; return __builtin_bit_cast(float, u); }
DEV u16 f2bf(float f){ unsigned u = __builtin_bit_cast(unsigned, f); u += 0x7FFFu + ((u >> 16) & 1u); return (u16)(u >> 16); }
DEV u16 f2h(float f){ _Float16 h = (_Float16)f; return __builtin_bit_cast(u16, h); }
DEV float h2f(u16 h){ return (float)__builtin_bit_cast(_Float16, h); }

DEV f32x4 mfma16(f16x8 a, f16x8 b, f32x4 c){
  return __builtin_amdgcn_mfma_f32_16x16x32_f16(a, b, c, 0, 0, 0);
}

// relu(fp16_a + fp16_b) packed pair -> v_pk_add_f16 + v_pk_max_f16
DEV unsigned rap(unsigned a, unsigned b){
  f16x2 ha = __builtin_bit_cast(f16x2, a);
  f16x2 hb = __builtin_bit_cast(f16x2, b);
  f16x2 s = ha + hb;
  const _Float16 z = (_Float16)0;
  s.x = s.x > z ? s.x : z;
  s.y = s.y > z ? s.y : z;
  return __builtin_bit_cast(unsigned, s);
}

DEV f16x8 build_frag(uint4 s, uint4 r){
  uint4 o;
  o.x = rap(s.x, r.x); o.y = rap(s.y, r.y);
  o.z = rap(s.z, r.z); o.w = rap(s.w, r.w);
  return __builtin_bit_cast(f16x8, o);
}

// Sizes: B=64, N=64, F=64, H=256, O=64, T=4, E=4032
// ws layout (bytes): FLAG@0 | W1T@256 | W2T@262400 | OW1T@393472 | OW2T@459008
//  | OW3T@590080 | B1@622848 | B2@624896 | OB1@625408 | OB2@625920 | OB3@626432
//  | S1@626688 (8.4MB, reused as H after k_edge) | R1@9015296 (8.4MB, reused as H2)
//  | AGG(f32)@17403904 (1MB) | RTT(fp16 [t][b][j][i])@18452480 (2MB) -> end 20549632
#define OFF_W1T  256
#define OFF_W2T  262400
#define OFF_OW1T 393472
#define OFF_OW2T 459008
#define OFF_OW3T 590080
#define OFF_B1   622848
#define OFF_B2   624896
#define OFF_OB1  625408
#define OFF_OB2  625920
#define OFF_OB3  626432
#define OFF_S1   626688
#define OFF_R1   9015296
#define OFF_AGG  17403904
#define OFF_RTT  18452480

DEV float ldin(const void* p, int i, int isbf){
  return isbf ? bf2f(((const u16*)p)[i]) : ((const float*)p)[i];
}

// in-block dtype sniff: wave 0 ballots on x's even u16s, LDS-broadcast.
DEV int sniff_isbf(const u16* x, int tid, int* sflag){
  if(tid < 64){
    u16 u = x[2 * tid];
    int e = (u >> 7) & 0xFF;
    int ok = (e >= 103 && e <= 143) ? 1 : 0;
    unsigned long long m = __ballot(ok);
    if(tid == 0) *sflag = (__builtin_popcountll(m) >= 40) ? 1 : 0;
  }
  __syncthreads();
  return *sflag;
}

// ---------------- K0: prep — weight transposes + biases + rel_type transpose + flag ----------------
__global__ __launch_bounds__(256) void k_prep(const void* __restrict__ x, const void* __restrict__ rt,
    const void* __restrict__ w1, const void* __restrict__ b1,
    const void* __restrict__ w2, const void* __restrict__ b2,
    const void* __restrict__ ow1, const void* __restrict__ ob1,
    const void* __restrict__ ow2, const void* __restrict__ ob2,
    const void* __restrict__ ow3, const void* __restrict__ ob3,
    char* __restrict__ ws){
  __shared__ float tile[32][33];
  __shared__ u16 sT[16384];          // [t][j][i] for rel transpose
  __shared__ int sflag;
  const int bid = blockIdx.x, tid = threadIdx.x;
  const int isbf = sniff_isbf((const u16*)x, tid, &sflag);
  if(bid >= 313){                    // rel_type transpose: one block per b, vectorized per-edge
    const int b = bid - 313;
    uint4 zz; zz.x = zz.y = zz.z = zz.w = 0;
    #pragma unroll
    for(int it=0; it<8; ++it) ((uint4*)sT)[tid + it*256] = zz;
    __syncthreads();
    #pragma unroll 1
    for(int it=0; it<16; ++it){
      int e = tid + it*256;          // edge index [0,4032)
      if(e < 4032){
        int i = e / 63, jr = e - i*63;
        int j = jr + (jr >= i ? 1 : 0);
        u16 w[4];
        if(isbf){
          ushort4 v = *(const ushort4*)((const u16*)rt + b*16128 + e*4);
          w[0] = f2h(bf2f(v.x)); w[1] = f2h(bf2f(v.y));
          w[2] = f2h(bf2f(v.z)); w[3] = f2h(bf2f(v.w));
        } else {
          float4 v = *(const float4*)((const float*)rt + b*16128 + e*4);
          w[0] = f2h(v.x); w[1] = f2h(v.y); w[2] = f2h(v.z); w[3] = f2h(v.w);
        }
        #pragma unroll
        for(int tt=0; tt<4; ++tt) sT[(tt*64 + j)*64 + i] = w[tt];
      }
    }
    __syncthreads();
    u16* RTT = (u16*)(ws + OFF_RTT);
    #pragma unroll
    for(int tt=0; tt<4; ++tt){
      uint4* dst = (uint4*)(RTT + ((tt*64 + b)*64)*64);
      const uint4* srcv = (const uint4*)(sT + tt*4096);
      #pragma unroll
      for(int it=0; it<2; ++it){
        int c = tid + it*256;        // [0,512)
        dst[c] = srcv[c];
      }
    }
    return;
  }
  if(bid == 312){ if(tid == 0) *(int*)ws = isbf; return; }
  if(bid >= 304){                    // biases: 1856 elems
    int n = (bid - 304) * 256 + tid;
    if(n < 1024){ ((u16*)(ws+OFF_B1))[n] = f2h(ldin(b1, n, isbf)); return; }
    n -= 1024;
    if(n < 256){ ((u16*)(ws+OFF_B2))[n] = f2h(ldin(b2, n, isbf)); return; }
    n -= 256;
    if(n < 256){ ((u16*)(ws+OFF_OB1))[n] = f2h(ldin(ob1, n, isbf)); return; }
    n -= 256;
    if(n < 256){ ((u16*)(ws+OFF_OB2))[n] = f2h(ldin(ob2, n, isbf)); return; }
    n -= 256;
    if(n < 64){ ((u16*)(ws+OFF_OB3))[n] = f2h(ldin(ob3, n, isbf)); }
    return;
  }
  // tiled transpose+convert: src [G][R][C] -> dst [G][C][R]
  const void* src; u16* dst; int R, C, off, r0, c0;
  if(bid < 128){ int g = bid >> 5, tt = bid & 31;
    src = w1; dst = (u16*)(ws + OFF_W1T); R = 128; C = 256; off = g * 32768;
    r0 = (tt >> 3) << 5; c0 = (tt & 7) << 5;
  } else if(bid < 192){ int bb = bid - 128; int g = bb >> 4, tt = bb & 15;
    src = w2; dst = (u16*)(ws + OFF_W2T); R = 256; C = 64; off = g * 16384;
    r0 = (tt >> 1) << 5; c0 = (tt & 1) << 5;
  } else if(bid < 224){ int bb = bid - 192;
    src = ow1; dst = (u16*)(ws + OFF_OW1T); R = 128; C = 256; off = 0;
    r0 = (bb >> 3) << 5; c0 = (bb & 7) << 5;
  } else if(bid < 288){ int bb = bid - 224;
    src = ow2; dst = (u16*)(ws + OFF_OW2T); R = 256; C = 256; off = 0;
    r0 = (bb >> 3) << 5; c0 = (bb & 7) << 5;
  } else { int bb = bid - 288;
    src = ow3; dst = (u16*)(ws + OFF_OW3T); R = 256; C = 64; off = 0;
    r0 = (bb >> 1) << 5; c0 = (bb & 1) << 5;
  }
  int tx = tid & 31, ty = tid >> 5;
  #pragma unroll
  for(int p = 0; p < 4; ++p){
    int r = ty + p * 8;
    tile[r][tx] = ldin(src, off + (r0 + r) * C + c0 + tx, isbf);
  }
  __syncthreads();
  #pragma unroll
  for(int p = 0; p < 4; ++p){
    int c = ty + p * 8;
    dst[off + (c0 + c) * R + r0 + tx] = f2h(tile[tx][c]);
  }
}

// ---------------- K1: S1/R1 = x @ w1-half (+b1 on receiver half); also zeroes AGG ----------------
__global__ __launch_bounds__(256) void k_s1r1(const void* __restrict__ x, const u16* __restrict__ W1T,
    const u16* __restrict__ B1c, u16* __restrict__ S1, u16* __restrict__ R1,
    float* __restrict__ AGG, const int* __restrict__ flag){
  __shared__ __align__(16) u16 sX[64][72];
  __shared__ __align__(16) u16 sW[256][72];
  const int tid = threadIdx.x, bid = blockIdx.x;
  const int b = bid & 63, th = bid >> 6, t = th >> 1, half = th & 1;
  const int isbf = *flag;
  {   // zero this block's 2KB slice of AGG (512 blocks x 2048B = 1MB exactly)
    float2 zz; zz.x = 0.f; zz.y = 0.f;
    ((float2*)AGG)[bid*256 + tid] = zz;
  }
  {
    if(isbf){
      const uint4* src = (const uint4*)((const u16*)x + b*4096);
      #pragma unroll
      for(int it=0; it<2; ++it){
        int c = tid + it*256; int row = c >> 3, col = (c & 7) * 8;
        uint4 v = src[c];
        const u16* pv = (const u16*)&v;
        u16 o[8];
        #pragma unroll
        for(int e=0;e<8;++e) o[e] = f2h(bf2f(pv[e]));
        *(uint4*)&sX[row][col] = *(const uint4*)o;
      }
    } else {
      const float* src = (const float*)x + b*4096;
      #pragma unroll
      for(int it=0; it<2; ++it){
        int c = tid + it*256; int row = c >> 3, col = (c & 7) * 8;
        u16 o[8];
        #pragma unroll
        for(int e=0;e<8;++e) o[e] = f2h(src[c*8 + e]);
        *(uint4*)&sX[row][col] = *(const uint4*)o;
      }
    }
    const u16* base = W1T + t*32768 + half*64;
    #pragma unroll
    for(int it=0; it<8; ++it){
      int c = tid + it*256; int h = c >> 3, kc = (c & 7) * 8;
      *(uint4*)&sW[h][kc] = *(const uint4*)(base + h*128 + kc);
    }
  }
  __syncthreads();
  const int wv = tid >> 6, l = tid & 63, ml = l & 15, q = l >> 4;
  const f32x4 z = {0.f,0.f,0.f,0.f};
  f32x4 acc[4][4];
  #pragma unroll
  for(int mt=0;mt<4;++mt){ acc[mt][0]=z; acc[mt][1]=z; acc[mt][2]=z; acc[mt][3]=z; }
  #pragma unroll
  for(int ks=0; ks<2; ++ks){
    const int kb = ks*32 + q*8;
    f16x8 af[4], bff[4];
    #pragma unroll
    for(int mt=0;mt<4;++mt) af[mt] = *(const f16x8*)&sX[mt*16 + ml][kb];
    #pragma unroll
    for(int nt=0;nt<4;++nt) bff[nt] = *(const f16x8*)&sW[wv*64 + nt*16 + ml][kb];
    #pragma unroll
    for(int mt=0;mt<4;++mt)
      #pragma unroll
      for(int nt=0;nt<4;++nt)
        acc[mt][nt] = mfma16(af[mt], bff[nt], acc[mt][nt]);
  }
  u16* dst = (half ? R1 : S1) + (t*64 + b)*16384;
  #pragma unroll
  for(int nt=0;nt<4;++nt){
    const int h = wv*64 + nt*16 + ml;
    const float bias = half ? h2f(B1c[t*256 + h]) : 0.0f;
    #pragma unroll
    for(int mt=0;mt<4;++mt)
      #pragma unroll
      for(int r=0;r<4;++r){
        int irow = mt*16 + q*4 + r;
        dst[irow*256 + h] = f2h(acc[mt][nt][r] + bias);
      }
  }
}

// ---------------- K2: per-edge layer-2 + weighted aggregation ----------------
// grid 512 = (t:4) x (b:64) x (jh:2). Waves = (ihalf x ohalf) quadrants.
// Each wave register-caches HALF of S1[t][b] (su, 64 VGPR) and HALF of W2T[t]
// (bf, 64 VGPR); main loop has ZERO LDS reads; only R1 row j streams from L2.
// Total regs ~220 < 256 -> honest 2 waves/SIMD, no spill (R5-R7 lesson).
__global__ __launch_bounds__(256, 2) void k_edge(const u16* __restrict__ RTT,
    const u16* __restrict__ W2T, const u16* __restrict__ B2c,
    const u16* __restrict__ S1, const u16* __restrict__ R1,
    float* __restrict__ AGG){
  __shared__ __align__(16) u16 sRT[32][64];    // [j-local][i] fp16 (4KB)
  __shared__ float sOut[2048];                 // [j-local][o] (8KB)
  const int tid = threadIdx.x, bid = blockIdx.x;
  const int t = bid >> 7, b = (bid >> 1) & 63, jh = bid & 1, j0 = jh * 32;
  const int w = tid >> 6, l = tid & 63, ml = l & 15, q = l >> 4;
  const int ih = w & 1, oh = w >> 1;
  #pragma unroll
  for(int it=0; it<8; ++it) sOut[tid + it*256] = 0.0f;
  // sRT: 32x64 fp16 = 256 uint4, one per lane
  ((uint4*)sRT)[tid] = ((const uint4*)(RTT + ((t*64 + b)*64 + j0)*64))[tid];
  __syncthreads();
  uint4 su[2][8];                    // S1 rows ih*32.. (64 VGPR)
  f16x8 bf[2][8];                    // W2T rows oh*32.. (64 VGPR)
  {
    const u16* s1b = S1 + (t*64 + b)*16384;
    const u16* w2t = W2T + t*16384;
    #pragma unroll
    for(int mt=0;mt<2;++mt)
      #pragma unroll
      for(int ks=0;ks<8;++ks)
        su[mt][ks] = *(const uint4*)(s1b + (ih*32 + mt*16 + ml)*256 + ks*32 + q*8);
    #pragma unroll
    for(int nt=0;nt<2;++nt)
      #pragma unroll
      for(int ks=0;ks<8;++ks)
        bf[nt][ks] = *(const f16x8*)(w2t + (oh*32 + nt*16 + ml)*256 + ks*32 + q*8);
  }
  float bias2[2];
  #pragma unroll
  for(int nt=0;nt<2;++nt) bias2[nt] = h2f(B2c[t*64 + oh*32 + nt*16 + ml]);
  const u16* r1b = R1 + (t*64 + b)*16384 + j0*256;
  const f32x4 z = {0.f,0.f,0.f,0.f};
  #pragma unroll 1
  for(int jl=0; jl<32; ++jl){
    uint4 ru[8];
    {
      const u16* rp = r1b + jl*256;
      #pragma unroll
      for(int ks=0;ks<8;++ks) ru[ks] = *(const uint4*)(rp + ks*32 + q*8);
    }
    f32x4 acc[2][2];
    acc[0][0]=z; acc[0][1]=z; acc[1][0]=z; acc[1][1]=z;
    #pragma unroll
    for(int ks=0;ks<8;++ks){
      #pragma unroll
      for(int mt=0;mt<2;++mt){
        f16x8 af = build_frag(su[mt][ks], ru[ks]);
        acc[mt][0] = mfma16(af, bf[0][ks], acc[mt][0]);
        acc[mt][1] = mfma16(af, bf[1][ks], acc[mt][1]);
      }
    }
    // epilogue: relu(C+b2), weight by rel_type over this wave's i-rows, col-sum
    float cs[2] = {0.f, 0.f};
    #pragma unroll
    for(int mt=0;mt<2;++mt){
      f16x4 rv = *(const f16x4*)&sRT[jl][ih*32 + mt*16 + q*4];
      #pragma unroll
      for(int nt=0;nt<2;++nt)
        #pragma unroll
        for(int r=0;r<4;++r)
          cs[nt] += fmaxf(acc[mt][nt][r] + bias2[nt], 0.0f) * (float)rv[r];
    }
    #pragma unroll
    for(int nt=0;nt<2;++nt){
      float v = cs[nt];
      v += __shfl_xor(v, 16, 64);
      v += __shfl_xor(v, 32, 64);
      if(q == 0) atomicAdd(&sOut[jl*64 + oh*32 + nt*16 + ml], v);  // combine ih 0/1
    }
  }
  __syncthreads();
  float* aggp = AGG + (b*64 + j0)*64;
  #pragma unroll
  for(int it=0; it<8; ++it){
    int c = tid + it*256;
    atomicAdd(&aggp[c], sOut[c]);
  }
}

// ---------------- K3a: node L1 — aug=[x,agg] @ OW1T + ob1, relu -> H ----------------
__global__ __launch_bounds__(256) void k_n1(const void* __restrict__ x, const float* __restrict__ AGG,
    const u16* __restrict__ OW1T, const u16* __restrict__ OB1c,
    u16* __restrict__ H, const int* __restrict__ flag){
  __shared__ __align__(16) u16 sA[64][136];
  __shared__ __align__(16) u16 sW[64][136];
  const int tid = threadIdx.x, bb = blockIdx.x & 63, nc = blockIdx.x >> 6;
  const int isbf = *flag;
  {
    if(isbf){
      const uint4* src = (const uint4*)((const u16*)x + bb*4096);
      #pragma unroll
      for(int it=0; it<2; ++it){
        int c = tid + it*256; int row = c >> 3, col = (c & 7)*8;
        uint4 v = src[c];
        const u16* pv = (const u16*)&v;
        u16 o[8];
        #pragma unroll
        for(int e=0;e<8;++e) o[e] = f2h(bf2f(pv[e]));
        *(uint4*)&sA[row][col] = *(const uint4*)o;
      }
    } else {
      const float* src = (const float*)x + bb*4096;
      #pragma unroll
      for(int it=0; it<2; ++it){
        int c = tid + it*256; int row = c >> 3, col = (c & 7)*8;
        u16 o[8];
        #pragma unroll
        for(int e=0;e<8;++e) o[e] = f2h(src[c*8 + e]);
        *(uint4*)&sA[row][col] = *(const uint4*)o;
      }
    }
    const float* ag = AGG + bb*4096;
    #pragma unroll
    for(int it=0; it<16; ++it){
      int c = tid + it*256; int row = c >> 6, col = c & 63;
      sA[row][64 + col] = f2h(ag[c]);
    }
    #pragma unroll
    for(int it=0; it<4; ++it){
      int c = tid + it*256; int h = c >> 4, kc = (c & 15)*8;
      *(uint4*)&sW[h][kc] = *(const uint4*)(OW1T + (nc*64 + h)*128 + kc);
    }
  }
  const int wv = tid >> 6, l = tid & 63, ml = l & 15, q = l >> 4;
  const f32x4 z = {0.f,0.f,0.f,0.f};
  __syncthreads();
  f32x4 acc[4] = {z,z,z,z};
  #pragma unroll
  for(int ks=0; ks<4; ++ks){
    int kb = ks*32 + q*8;
    f16x8 bfrag = *(const f16x8*)&sW[wv*16 + ml][kb];
    #pragma unroll
    for(int mt=0;mt<4;++mt){
      f16x8 afrag = *(const f16x8*)&sA[mt*16 + ml][kb];
      acc[mt] = mfma16(afrag, bfrag, acc[mt]);
    }
  }
  const int h = nc*64 + wv*16 + ml;
  const float bias = h2f(OB1c[h]);
  #pragma unroll
  for(int mt=0;mt<4;++mt)
    #pragma unroll
    for(int r=0;r<4;++r){
      int row = mt*16 + q*4 + r;
      H[(bb*64 + row)*256 + h] = f2h(fmaxf(acc[mt][r] + bias, 0.0f));
    }
}

// ---------------- K3b: node L2 — H @ OW2T + ob2, relu -> H2 ----------------
__global__ __launch_bounds__(256) void k_n2(const u16* __restrict__ H,
    const u16* __restrict__ OW2T, const u16* __restrict__ OB2c,
    u16* __restrict__ H2){
  __shared__ __align__(16) u16 sH[64][264];
  __shared__ __align__(16) u16 sW[64][264];
  const int tid = threadIdx.x, bb = blockIdx.x & 63, nc = blockIdx.x >> 6;
  {
    const uint4* hp = (const uint4*)(H + bb*16384);
    #pragma unroll
    for(int it=0; it<8; ++it){
      int c = tid + it*256; int row = c >> 5, col = (c & 31)*8;
      *(uint4*)&sH[row][col] = hp[c];
      *(uint4*)&sW[row][col] = *(const uint4*)(OW2T + nc*16384 + c*8);
    }
  }
  const int wv = tid >> 6, l = tid & 63, ml = l & 15, q = l >> 4;
  const f32x4 z = {0.f,0.f,0.f,0.f};
  __syncthreads();
  f32x4 acc[4] = {z,z,z,z};
  #pragma unroll
  for(int ks=0; ks<8; ++ks){
    int kb = ks*32 + q*8;
    f16x8 bfrag = *(const f16x8*)&sW[wv*16 + ml][kb];
    #pragma unroll
    for(int mt=0;mt<4;++mt){
      f16x8 afrag = *(const f16x8*)&sH[mt*16 + ml][kb];
      acc[mt] = mfma16(afrag, bfrag, acc[mt]);
    }
  }
  const int h = nc*64 + wv*16 + ml;
  const float bias = h2f(OB2c[h]);
  #pragma unroll
  for(int mt=0;mt<4;++mt)
    #pragma unroll
    for(int r=0;r<4;++r){
      int row = mt*16 + q*4 + r;
      H2[(bb*64 + row)*256 + h] = f2h(fmaxf(acc[mt][r] + bias, 0.0f));
    }
}

// ---------------- K3c: node L3 — H2 @ OW3T + ob3 -> out ----------------
__global__ __launch_bounds__(256) void k_n3(const u16* __restrict__ H2,
    const u16* __restrict__ OW3T, const u16* __restrict__ OB3c,
    void* __restrict__ out, const int* __restrict__ flag){
  __shared__ __align__(16) u16 sH[64][264];
  __shared__ __align__(16) u16 sW[64][264];
  const int tid = threadIdx.x, bb = blockIdx.x;
  const int isbf = *flag;
  {
    const uint4* hp = (const uint4*)(H2 + bb*16384);
    #pragma unroll
    for(int it=0; it<8; ++it){
      int c = tid + it*256; int row = c >> 5, col = (c & 31)*8;
      *(uint4*)&sH[row][col] = hp[c];
      *(uint4*)&sW[row][col] = *(const uint4*)(OW3T + c*8);
    }
  }
  const int wv = tid >> 6, l = tid & 63, ml = l & 15, q = l >> 4;
  const f32x4 z = {0.f,0.f,0.f,0.f};
  __syncthreads();
  f32x4 acc[4] = {z,z,z,z};
  #pragma unroll
  for(int ks=0; ks<8; ++ks){
    int kb = ks*32 + q*8;
    f16x8 bfrag = *(const f16x8*)&sW[wv*16 + ml][kb];
    #pragma unroll
    for(int mt=0;mt<4;++mt){
      f16x8 afrag = *(const f16x8*)&sH[mt*16 + ml][kb];
      acc[mt] = mfma16(afrag, bfrag, acc[mt]);
    }
  }
  const int o = wv*16 + ml;
  const float bias = h2f(OB3c[o]);
  #pragma unroll
  for(int mt=0;mt<4;++mt)
    #pragma unroll
    for(int r=0;r<4;++r){
      int row = mt*16 + q*4 + r;
      float v = acc[mt][r] + bias;
      int idx = bb*4096 + row*64 + o;
      if(isbf) ((u16*)out)[idx] = f2bf(v);
      else     ((float*)out)[idx] = v;
    }
}

extern "C" void kernel_launch(void* const* d_in, const int* in_sizes, int n_in,
                              void* d_out, int out_size, void* d_ws, size_t ws_size,
                              hipStream_t stream){
  (void)in_sizes; (void)n_in; (void)out_size; (void)ws_size;
  char* ws = (char*)d_ws;
  u16* W1T  = (u16*)(ws + OFF_W1T);
  u16* W2T  = (u16*)(ws + OFF_W2T);
  u16* OW1T = (u16*)(ws + OFF_OW1T);
  u16* OW2T = (u16*)(ws + OFF_OW2T);
  u16* OW3T = (u16*)(ws + OFF_OW3T);
  u16* B1c  = (u16*)(ws + OFF_B1);
  u16* B2c  = (u16*)(ws + OFF_B2);
  u16* OB1c = (u16*)(ws + OFF_OB1);
  u16* OB2c = (u16*)(ws + OFF_OB2);
  u16* OB3c = (u16*)(ws + OFF_OB3);
  u16* S1   = (u16*)(ws + OFF_S1);
  u16* R1   = (u16*)(ws + OFF_R1);
  float* AGG = (float*)(ws + OFF_AGG);
  u16* RTT  = (u16*)(ws + OFF_RTT);
  u16* H    = (u16*)(ws + OFF_S1);   // alias: S1 dead after k_edge
  u16* H2   = (u16*)(ws + OFF_R1);   // alias: R1 dead after k_edge
  const int* flag = (const int*)ws;

  k_prep<<<377, 256, 0, stream>>>(d_in[0], d_in[1], d_in[4], d_in[5], d_in[6], d_in[7],
                                  d_in[8], d_in[9], d_in[10], d_in[11], d_in[12], d_in[13], ws);
  k_s1r1<<<512, 256, 0, stream>>>(d_in[0], W1T, B1c, S1, R1, AGG, flag);
  k_edge<<<512, 256, 0, stream>>>(RTT, W2T, B2c, S1, R1, AGG);
  k_n1<<<256, 256, 0, stream>>>(d_in[0], AGG, OW1T, OB1c, H, flag);
  k_n2<<<256, 256, 0, stream>>>(H, OW2T, OB2c, H2);
  k_n3<<<64, 256, 0, stream>>>(H2, OW3T, OB3c, d_out, flag);
}

// Round 9
// 180.916 us; speedup vs baseline: 1.4932x; 1.0685x over previous
//
#include <hip/hip_runtime.h>

typedef unsigned short u16;
typedef __attribute__((ext_vector_type(8))) _Float16 f16x8;
typedef __attribute__((ext_vector_type(4))) _Float16 f16x4;
typedef __attribute__((ext_vector_type(2))) _Float16 f16x2;
typedef __attribute__((ext_vector_type(4))) float f32x4;

#define DEV static __device__ __forceinline__

DEV float bf2f(u16 h){ unsigned u = ((unsigned)h) << 16; return __builtin_bit_cast(float, u); }
DEV u16 f2bf(float f){ unsigned u = __builtin_bit_cast(unsigned, f); u += 0x7FFFu + ((u >> 16) & 1u); return (u16)(u >> 16); }
DEV u16 f2h(float f){ _Float16 h = (_Float16)f; return __builtin_bit_cast(u16, h); }
DEV float h2f(u16 h){ return (float)__builtin_bit_cast(_Float16, h); }

DEV f32x4 mfma16(f16x8 a, f16x8 b, f32x4 c){
  return __builtin_amdgcn_mfma_f32_16x16x32_f16(a, b, c, 0, 0, 0);
}

// relu(fp16_a + fp16_b) packed pair -> v_pk_add_f16 + v_pk_max_f16
DEV unsigned rap(unsigned a, unsigned b){
  f16x2 ha = __builtin_bit_cast(f16x2, a);
  f16x2 hb = __builtin_bit_cast(f16x2, b);
  f16x2 s = ha + hb;
  const _Float16 z = (_Float16)0;
  s.x = s.x > z ? s.x : z;
  s.y = s.y > z ? s.y : z;
  return __builtin_bit_cast(unsigned, s);
}

DEV f16x8 build_frag(uint4 s, uint4 r){
  uint4 o;
  o.x = rap(s.x, r.x); o.y = rap(s.y, r.y);
  o.z = rap(s.z, r.z); o.w = rap(s.w, r.w);
  return __builtin_bit_cast(f16x8, o);
}

// Sizes: B=64, N=64, F=64, H=256, O=64, T=4, E=4032
// ws layout (bytes): FLAG@0 | W1T@256 | W2T@262400 | OW1T@393472 | OW2T@459008
//  | OW3T@590080 | B1@622848 | B2@624896 | OB1@625408 | OB2@625920 | OB3@626432
//  | S1@626688 (8.4MB, reused as H after k_edge) | R1@9015296 (8.4MB, reused as H2)
//  | AGG(f32)@17403904 (1MB) | RTT(fp16 [t][b][j][i])@18452480 (2MB) -> end 20549632
#define OFF_W1T  256
#define OFF_W2T  262400
#define OFF_OW1T 393472
#define OFF_OW2T 459008
#define OFF_OW3T 590080
#define OFF_B1   622848
#define OFF_B2   624896
#define OFF_OB1  625408
#define OFF_OB2  625920
#define OFF_OB3  626432
#define OFF_S1   626688
#define OFF_R1   9015296
#define OFF_AGG  17403904
#define OFF_RTT  18452480

DEV float ldin(const void* p, int i, int isbf){
  return isbf ? bf2f(((const u16*)p)[i]) : ((const float*)p)[i];
}

// in-block dtype sniff: wave 0 ballots on x's even u16s, LDS-broadcast.
DEV int sniff_isbf(const u16* x, int tid, int* sflag){
  if(tid < 64){
    u16 u = x[2 * tid];
    int e = (u >> 7) & 0xFF;
    int ok = (e >= 103 && e <= 143) ? 1 : 0;
    unsigned long long m = __ballot(ok);
    if(tid == 0) *sflag = (__builtin_popcountll(m) >= 40) ? 1 : 0;
  }
  __syncthreads();
  return *sflag;
}

// ---------------- K0: prep — weight transposes + biases + rel_type transpose + flag ----------------
__global__ __launch_bounds__(256) void k_prep(const void* __restrict__ x, const void* __restrict__ rt,
    const void* __restrict__ w1, const void* __restrict__ b1,
    const void* __restrict__ w2, const void* __restrict__ b2,
    const void* __restrict__ ow1, const void* __restrict__ ob1,
    const void* __restrict__ ow2, const void* __restrict__ ob2,
    const void* __restrict__ ow3, const void* __restrict__ ob3,
    char* __restrict__ ws){
  __shared__ float tile[32][33];
  __shared__ u16 sT[16384];          // [t][j][i] for rel transpose
  __shared__ int sflag;
  const int bid = blockIdx.x, tid = threadIdx.x;
  const int isbf = sniff_isbf((const u16*)x, tid, &sflag);
  if(bid >= 313){                    // rel_type transpose: one block per b, vectorized per-edge
    const int b = bid - 313;
    uint4 zz; zz.x = zz.y = zz.z = zz.w = 0;
    #pragma unroll
    for(int it=0; it<8; ++it) ((uint4*)sT)[tid + it*256] = zz;
    __syncthreads();
    #pragma unroll 1
    for(int it=0; it<16; ++it){
      int e = tid + it*256;          // edge index [0,4032)
      if(e < 4032){
        int i = e / 63, jr = e - i*63;
        int j = jr + (jr >= i ? 1 : 0);
        u16 w[4];
        if(isbf){
          ushort4 v = *(const ushort4*)((const u16*)rt + b*16128 + e*4);
          w[0] = f2h(bf2f(v.x)); w[1] = f2h(bf2f(v.y));
          w[2] = f2h(bf2f(v.z)); w[3] = f2h(bf2f(v.w));
        } else {
          float4 v = *(const float4*)((const float*)rt + b*16128 + e*4);
          w[0] = f2h(v.x); w[1] = f2h(v.y); w[2] = f2h(v.z); w[3] = f2h(v.w);
        }
        #pragma unroll
        for(int tt=0; tt<4; ++tt) sT[(tt*64 + j)*64 + i] = w[tt];
      }
    }
    __syncthreads();
    u16* RTT = (u16*)(ws + OFF_RTT);
    #pragma unroll
    for(int tt=0; tt<4; ++tt){
      uint4* dst = (uint4*)(RTT + ((tt*64 + b)*64)*64);
      const uint4* srcv = (const uint4*)(sT + tt*4096);
      #pragma unroll
      for(int it=0; it<2; ++it){
        int c = tid + it*256;        // [0,512)
        dst[c] = srcv[c];
      }
    }
    return;
  }
  if(bid == 312){ if(tid == 0) *(int*)ws = isbf; return; }
  if(bid >= 304){                    // biases: 1856 elems
    int n = (bid - 304) * 256 + tid;
    if(n < 1024){ ((u16*)(ws+OFF_B1))[n] = f2h(ldin(b1, n, isbf)); return; }
    n -= 1024;
    if(n < 256){ ((u16*)(ws+OFF_B2))[n] = f2h(ldin(b2, n, isbf)); return; }
    n -= 256;
    if(n < 256){ ((u16*)(ws+OFF_OB1))[n] = f2h(ldin(ob1, n, isbf)); return; }
    n -= 256;
    if(n < 256){ ((u16*)(ws+OFF_OB2))[n] = f2h(ldin(ob2, n, isbf)); return; }
    n -= 256;
    if(n < 64){ ((u16*)(ws+OFF_OB3))[n] = f2h(ldin(ob3, n, isbf)); }
    return;
  }
  // tiled transpose+convert: src [G][R][C] -> dst [G][C][R]
  const void* src; u16* dst; int R, C, off, r0, c0;
  if(bid < 128){ int g = bid >> 5, tt = bid & 31;
    src = w1; dst = (u16*)(ws + OFF_W1T); R = 128; C = 256; off = g * 32768;
    r0 = (tt >> 3) << 5; c0 = (tt & 7) << 5;
  } else if(bid < 192){ int bb = bid - 128; int g = bb >> 4, tt = bb & 15;
    src = w2; dst = (u16*)(ws + OFF_W2T); R = 256; C = 64; off = g * 16384;
    r0 = (tt >> 1) << 5; c0 = (tt & 1) << 5;
  } else if(bid < 224){ int bb = bid - 192;
    src = ow1; dst = (u16*)(ws + OFF_OW1T); R = 128; C = 256; off = 0;
    r0 = (bb >> 3) << 5; c0 = (bb & 7) << 5;
  } else if(bid < 288){ int bb = bid - 224;
    src = ow2; dst = (u16*)(ws + OFF_OW2T); R = 256; C = 256; off = 0;
    r0 = (bb >> 3) << 5; c0 = (bb & 7) << 5;
  } else { int bb = bid - 288;
    src = ow3; dst = (u16*)(ws + OFF_OW3T); R = 256; C = 64; off = 0;
    r0 = (bb >> 1) << 5; c0 = (bb & 1) << 5;
  }
  int tx = tid & 31, ty = tid >> 5;
  #pragma unroll
  for(int p = 0; p < 4; ++p){
    int r = ty + p * 8;
    tile[r][tx] = ldin(src, off + (r0 + r) * C + c0 + tx, isbf);
  }
  __syncthreads();
  #pragma unroll
  for(int p = 0; p < 4; ++p){
    int c = ty + p * 8;
    dst[off + (c0 + c) * R + r0 + tx] = f2h(tile[tx][c]);
  }
}

// ---------------- K1: S1/R1 = x @ w1-half (+b1 on receiver half); also zeroes AGG ----------------
__global__ __launch_bounds__(256) void k_s1r1(const void* __restrict__ x, const u16* __restrict__ W1T,
    const u16* __restrict__ B1c, u16* __restrict__ S1, u16* __restrict__ R1,
    float* __restrict__ AGG, const int* __restrict__ flag){
  __shared__ __align__(16) u16 sX[64][72];
  __shared__ __align__(16) u16 sW[256][72];
  const int tid = threadIdx.x, bid = blockIdx.x;
  const int b = bid & 63, th = bid >> 6, t = th >> 1, half = th & 1;
  const int isbf = *flag;
  {   // zero this block's 2KB slice of AGG (512 blocks x 2048B = 1MB exactly)
    float2 zz; zz.x = 0.f; zz.y = 0.f;
    ((float2*)AGG)[bid*256 + tid] = zz;
  }
  {
    if(isbf){
      const uint4* src = (const uint4*)((const u16*)x + b*4096);
      #pragma unroll
      for(int it=0; it<2; ++it){
        int c = tid + it*256; int row = c >> 3, col = (c & 7) * 8;
        uint4 v = src[c];
        const u16* pv = (const u16*)&v;
        u16 o[8];
        #pragma unroll
        for(int e=0;e<8;++e) o[e] = f2h(bf2f(pv[e]));
        *(uint4*)&sX[row][col] = *(const uint4*)o;
      }
    } else {
      const float* src = (const float*)x + b*4096;
      #pragma unroll
      for(int it=0; it<2; ++it){
        int c = tid + it*256; int row = c >> 3, col = (c & 7) * 8;
        u16 o[8];
        #pragma unroll
        for(int e=0;e<8;++e) o[e] = f2h(src[c*8 + e]);
        *(uint4*)&sX[row][col] = *(const uint4*)o;
      }
    }
    const u16* base = W1T + t*32768 + half*64;
    #pragma unroll
    for(int it=0; it<8; ++it){
      int c = tid + it*256; int h = c >> 3, kc = (c & 7) * 8;
      *(uint4*)&sW[h][kc] = *(const uint4*)(base + h*128 + kc);
    }
  }
  __syncthreads();
  const int wv = tid >> 6, l = tid & 63, ml = l & 15, q = l >> 4;
  const f32x4 z = {0.f,0.f,0.f,0.f};
  f32x4 acc[4][4];
  #pragma unroll
  for(int mt=0;mt<4;++mt){ acc[mt][0]=z; acc[mt][1]=z; acc[mt][2]=z; acc[mt][3]=z; }
  #pragma unroll
  for(int ks=0; ks<2; ++ks){
    const int kb = ks*32 + q*8;
    f16x8 af[4], bff[4];
    #pragma unroll
    for(int mt=0;mt<4;++mt) af[mt] = *(const f16x8*)&sX[mt*16 + ml][kb];
    #pragma unroll
    for(int nt=0;nt<4;++nt) bff[nt] = *(const f16x8*)&sW[wv*64 + nt*16 + ml][kb];
    #pragma unroll
    for(int mt=0;mt<4;++mt)
      #pragma unroll
      for(int nt=0;nt<4;++nt)
        acc[mt][nt] = mfma16(af[mt], bff[nt], acc[mt][nt]);
  }
  u16* dst = (half ? R1 : S1) + (t*64 + b)*16384;
  #pragma unroll
  for(int nt=0;nt<4;++nt){
    const int h = wv*64 + nt*16 + ml;
    const float bias = half ? h2f(B1c[t*256 + h]) : 0.0f;
    #pragma unroll
    for(int mt=0;mt<4;++mt)
      #pragma unroll
      for(int r=0;r<4;++r){
        int irow = mt*16 + q*4 + r;
        dst[irow*256 + h] = f2h(acc[mt][nt][r] + bias);
      }
  }
}

// ---------------- K2: per-edge layer-2 + weighted aggregation ----------------
// grid 512 = (t:4) x (b:64) x (jh:2), launch_bounds(256,1) — R5/R7/R8 lesson:
// min-waves=2 makes the allocator cap ~128 VGPR and spill/remat. Here:
// su = FULL S1[t][b] register-resident (128 VGPR, loaded once); W2T[t] in LDS
// (shared by all 4 same-t waves, 4 ds_read_b128 per ks < MFMA time); ru[8]
// batched per j. ~250 regs -> 2 waves/SIMD. Waves own disjoint j's -> sOut
// plain stores; cross-t combine via global atomics (AGG zeroed in k_s1r1).
__global__ __launch_bounds__(256) void k_edge(const u16* __restrict__ RTT,
    const u16* __restrict__ W2T, const u16* __restrict__ B2c,
    const u16* __restrict__ S1, const u16* __restrict__ R1,
    float* __restrict__ AGG){
  __shared__ __align__(16) u16 sW2[64][264];   // [o][k], +8 pad (33KB)
  __shared__ __align__(16) u16 sRT[32][64];    // [j-local][i] fp16 (4KB)
  __shared__ float sOut[2048];                 // [j-local][o] (8KB)
  const int tid = threadIdx.x, bid = blockIdx.x;
  const int t = bid >> 7, b = (bid >> 1) & 63, jh = bid & 1, j0 = jh * 32;
  {
    const uint4* w2p = (const uint4*)(W2T + t*16384);
    #pragma unroll
    for(int it=0; it<8; ++it){
      int c = tid + it*256;                 // 0..2047
      int row = c >> 5, col = (c & 31) * 8;
      *(uint4*)&sW2[row][col] = w2p[c];
    }
    // sRT: 32x64 fp16 = 4096B = 256 uint4, one per lane
    ((uint4*)sRT)[tid] = ((const uint4*)(RTT + ((t*64 + b)*64 + j0)*64))[tid];
  }
  __syncthreads();
  const int w = tid >> 6, l = tid & 63, ml = l & 15, q = l >> 4;
  uint4 su[4][8];                    // full S1[t][b] A-side: 128 VGPR, loaded ONCE
  {
    const u16* s1b = S1 + (t*64 + b)*16384;
    #pragma unroll
    for(int mt=0;mt<4;++mt)
      #pragma unroll
      for(int ks=0;ks<8;++ks)
        su[mt][ks] = *(const uint4*)(s1b + (mt*16 + ml)*256 + ks*32 + q*8);
  }
  float bias2[4];
  #pragma unroll
  for(int nt=0;nt<4;++nt) bias2[nt] = h2f(B2c[t*64 + nt*16 + ml]);
  const u16* r1b = R1 + (t*64 + b)*16384 + j0*256;
  const f32x4 z = {0.f,0.f,0.f,0.f};
  #pragma unroll 1
  for(int jp=0; jp<8; ++jp){
    const int jl = w*8 + jp;           // this wave's receiver (j-local in [0,32))
    uint4 ru[8];
    {
      const u16* rp = r1b + jl*256;
      #pragma unroll
      for(int ks=0;ks<8;++ks) ru[ks] = *(const uint4*)(rp + ks*32 + q*8);
    }
    f32x4 acc[4][4];
    #pragma unroll
    for(int mt=0;mt<4;++mt){ acc[mt][0]=z; acc[mt][1]=z; acc[mt][2]=z; acc[mt][3]=z; }
    #pragma unroll
    for(int ks=0;ks<8;++ks){
      const int kb = ks*32 + q*8;
      f16x8 bf[4];
      #pragma unroll
      for(int nt=0;nt<4;++nt) bf[nt] = *(const f16x8*)&sW2[nt*16 + ml][kb];
      #pragma unroll
      for(int mt=0;mt<4;++mt){
        f16x8 af = build_frag(su[mt][ks], ru[ks]);   // relu(S1+R1) in-register
        #pragma unroll
        for(int nt=0;nt<4;++nt) acc[mt][nt] = mfma16(af, bf[nt], acc[mt][nt]);
      }
    }
    // epilogue: relu(C+b2), weight by rel_type, column-sum over sender rows i
    float cs[4] = {0.f,0.f,0.f,0.f};
    #pragma unroll
    for(int mt=0;mt<4;++mt){
      f16x4 rv = *(const f16x4*)&sRT[jl][mt*16 + q*4];
      #pragma unroll
      for(int nt=0;nt<4;++nt)
        #pragma unroll
        for(int r=0;r<4;++r)
          cs[nt] += fmaxf(acc[mt][nt][r] + bias2[nt], 0.0f) * (float)rv[r];
    }
    #pragma unroll
    for(int nt=0;nt<4;++nt){
      float v = cs[nt];
      v += __shfl_xor(v, 16, 64);
      v += __shfl_xor(v, 32, 64);
      if(q == 0) sOut[jl*64 + nt*16 + ml] = v;   // disjoint j per wave: plain store
    }
  }
  __syncthreads();
  float* aggp = AGG + (b*64 + j0)*64;
  #pragma unroll
  for(int it=0; it<8; ++it){
    int c = tid + it*256;
    atomicAdd(&aggp[c], sOut[c]);      // combine 4 t-blocks
  }
}

// ---------------- K3a: node L1 — aug=[x,agg] @ OW1T + ob1, relu -> H ----------------
__global__ __launch_bounds__(256) void k_n1(const void* __restrict__ x, const float* __restrict__ AGG,
    const u16* __restrict__ OW1T, const u16* __restrict__ OB1c,
    u16* __restrict__ H, const int* __restrict__ flag){
  __shared__ __align__(16) u16 sA[64][136];
  __shared__ __align__(16) u16 sW[64][136];
  const int tid = threadIdx.x, bb = blockIdx.x & 63, nc = blockIdx.x >> 6;
  const int isbf = *flag;
  {
    if(isbf){
      const uint4* src = (const uint4*)((const u16*)x + bb*4096);
      #pragma unroll
      for(int it=0; it<2; ++it){
        int c = tid + it*256; int row = c >> 3, col = (c & 7)*8;
        uint4 v = src[c];
        const u16* pv = (const u16*)&v;
        u16 o[8];
        #pragma unroll
        for(int e=0;e<8;++e) o[e] = f2h(bf2f(pv[e]));
        *(uint4*)&sA[row][col] = *(const uint4*)o;
      }
    } else {
      const float* src = (const float*)x + bb*4096;
      #pragma unroll
      for(int it=0; it<2; ++it){
        int c = tid + it*256; int row = c >> 3, col = (c & 7)*8;
        u16 o[8];
        #pragma unroll
        for(int e=0;e<8;++e) o[e] = f2h(src[c*8 + e]);
        *(uint4*)&sA[row][col] = *(const uint4*)o;
      }
    }
    const float* ag = AGG + bb*4096;
    #pragma unroll
    for(int it=0; it<16; ++it){
      int c = tid + it*256; int row = c >> 6, col = c & 63;
      sA[row][64 + col] = f2h(ag[c]);
    }
    #pragma unroll
    for(int it=0; it<4; ++it){
      int c = tid + it*256; int h = c >> 4, kc = (c & 15)*8;
      *(uint4*)&sW[h][kc] = *(const uint4*)(OW1T + (nc*64 + h)*128 + kc);
    }
  }
  const int wv = tid >> 6, l = tid & 63, ml = l & 15, q = l >> 4;
  const f32x4 z = {0.f,0.f,0.f,0.f};
  __syncthreads();
  f32x4 acc[4] = {z,z,z,z};
  #pragma unroll
  for(int ks=0; ks<4; ++ks){
    int kb = ks*32 + q*8;
    f16x8 bfrag = *(const f16x8*)&sW[wv*16 + ml][kb];
    #pragma unroll
    for(int mt=0;mt<4;++mt){
      f16x8 afrag = *(const f16x8*)&sA[mt*16 + ml][kb];
      acc[mt] = mfma16(afrag, bfrag, acc[mt]);
    }
  }
  const int h = nc*64 + wv*16 + ml;
  const float bias = h2f(OB1c[h]);
  #pragma unroll
  for(int mt=0;mt<4;++mt)
    #pragma unroll
    for(int r=0;r<4;++r){
      int row = mt*16 + q*4 + r;
      H[(bb*64 + row)*256 + h] = f2h(fmaxf(acc[mt][r] + bias, 0.0f));
    }
}

// ---------------- K3b: node L2 — H @ OW2T + ob2, relu -> H2 ----------------
__global__ __launch_bounds__(256) void k_n2(const u16* __restrict__ H,
    const u16* __restrict__ OW2T, const u16* __restrict__ OB2c,
    u16* __restrict__ H2){
  __shared__ __align__(16) u16 sH[64][264];
  __shared__ __align__(16) u16 sW[64][264];
  const int tid = threadIdx.x, bb = blockIdx.x & 63, nc = blockIdx.x >> 6;
  {
    const uint4* hp = (const uint4*)(H + bb*16384);
    #pragma unroll
    for(int it=0; it<8; ++it){
      int c = tid + it*256; int row = c >> 5, col = (c & 31)*8;
      *(uint4*)&sH[row][col] = hp[c];
      *(uint4*)&sW[row][col] = *(const uint4*)(OW2T + nc*16384 + c*8);
    }
  }
  const int wv = tid >> 6, l = tid & 63, ml = l & 15, q = l >> 4;
  const f32x4 z = {0.f,0.f,0.f,0.f};
  __syncthreads();
  f32x4 acc[4] = {z,z,z,z};
  #pragma unroll
  for(int ks=0; ks<8; ++ks){
    int kb = ks*32 + q*8;
    f16x8 bfrag = *(const f16x8*)&sW[wv*16 + ml][kb];
    #pragma unroll
    for(int mt=0;mt<4;++mt){
      f16x8 afrag = *(const f16x8*)&sH[mt*16 + ml][kb];
      acc[mt] = mfma16(afrag, bfrag, acc[mt]);
    }
  }
  const int h = nc*64 + wv*16 + ml;
  const float bias = h2f(OB2c[h]);
  #pragma unroll
  for(int mt=0;mt<4;++mt)
    #pragma unroll
    for(int r=0;r<4;++r){
      int row = mt*16 + q*4 + r;
      H2[(bb*64 + row)*256 + h] = f2h(fmaxf(acc[mt][r] + bias, 0.0f));
    }
}

// ---------------- K3c: node L3 — H2 @ OW3T + ob3 -> out ----------------
__global__ __launch_bounds__(256) void k_n3(const u16* __restrict__ H2,
    const u16* __restrict__ OW3T, const u16* __restrict__ OB3c,
    void* __restrict__ out, const int* __restrict__ flag){
  __shared__ __align__(16) u16 sH[64][264];
  __shared__ __align__(16) u16 sW[64][264];
  const int tid = threadIdx.x, bb = blockIdx.x;
  const int isbf = *flag;
  {
    const uint4* hp = (const uint4*)(H2 + bb*16384);
    #pragma unroll
    for(int it=0; it<8; ++it){
      int c = tid + it*256; int row = c >> 5, col = (c & 31)*8;
      *(uint4*)&sH[row][col] = hp[c];
      *(uint4*)&sW[row][col] = *(const uint4*)(OW3T + c*8);
    }
  }
  const int wv = tid >> 6, l = tid & 63, ml = l & 15, q = l >> 4;
  const f32x4 z = {0.f,0.f,0.f,0.f};
  __syncthreads();
  f32x4 acc[4] = {z,z,z,z};
  #pragma unroll
  for(int ks=0; ks<8; ++ks){
    int kb = ks*32 + q*8;
    f16x8 bfrag = *(const f16x8*)&sW[wv*16 + ml][kb];
    #pragma unroll
    for(int mt=0;mt<4;++mt){
      f16x8 afrag = *(const f16x8*)&sH[mt*16 + ml][kb];
      acc[mt] = mfma16(afrag, bfrag, acc[mt]);
    }
  }
  const int o = wv*16 + ml;
  const float bias = h2f(OB3c[o]);
  #pragma unroll
  for(int mt=0;mt<4;++mt)
    #pragma unroll
    for(int r=0;r<4;++r){
      int row = mt*16 + q*4 + r;
      float v = acc[mt][r] + bias;
      int idx = bb*4096 + row*64 + o;
      if(isbf) ((u16*)out)[idx] = f2bf(v);
      else     ((float*)out)[idx] = v;
    }
}

extern "C" void kernel_launch(void* const* d_in, const int* in_sizes, int n_in,
                              void* d_out, int out_size, void* d_ws, size_t ws_size,
                              hipStream_t stream){
  (void)in_sizes; (void)n_in; (void)out_size; (void)ws_size;
  char* ws = (char*)d_ws;
  u16* W1T  = (u16*)(ws + OFF_W1T);
  u16* W2T  = (u16*)(ws + OFF_W2T);
  u16* OW1T = (u16*)(ws + OFF_OW1T);
  u16* OW2T = (u16*)(ws + OFF_OW2T);
  u16* OW3T = (u16*)(ws + OFF_OW3T);
  u16* B1c  = (u16*)(ws + OFF_B1);
  u16* B2c  = (u16*)(ws + OFF_B2);
  u16* OB1c = (u16*)(ws + OFF_OB1);
  u16* OB2c = (u16*)(ws + OFF_OB2);
  u16* OB3c = (u16*)(ws + OFF_OB3);
  u16* S1   = (u16*)(ws + OFF_S1);
  u16* R1   = (u16*)(ws + OFF_R1);
  float* AGG = (float*)(ws + OFF_AGG);
  u16* RTT  = (u16*)(ws + OFF_RTT);
  u16* H    = (u16*)(ws + OFF_S1);   // alias: S1 dead after k_edge
  u16* H2   = (u16*)(ws + OFF_R1);   // alias: R1 dead after k_edge
  const int* flag = (const int*)ws;

  k_prep<<<377, 256, 0, stream>>>(d_in[0], d_in[1], d_in[4], d_in[5], d_in[6], d_in[7],
                                  d_in[8], d_in[9], d_in[10], d_in[11], d_in[12], d_in[13], ws);
  k_s1r1<<<512, 256, 0, stream>>>(d_in[0], W1T, B1c, S1, R1, AGG, flag);
  k_edge<<<512, 256, 0, stream>>>(RTT, W2T, B2c, S1, R1, AGG);
  k_n1<<<256, 256, 0, stream>>>(d_in[0], AGG, OW1T, OB1c, H, flag);
  k_n2<<<256, 256, 0, stream>>>(H, OW2T, OB2c, H2);
  k_n3<<<64, 256, 0, stream>>>(H2, OW3T, OB3c, d_out, flag);
}